// Round 4
// baseline (132.013 us; speedup 1.0000x reference)
//
#include <hip/hip_runtime.h>
#include <hip/hip_bf16.h>

#define NP 512   // particles
#define DD 128   // dims

typedef float f4_ext __attribute__((ext_vector_type(4)));

// ---------------------------------------------------------------------------
// Kernel 1: per-dimension exact median of upper-triangular pairwise squared
// differences. One block (512 threads) per dimension d.
//   1) hybrid bitonic sort of 512 values: __shfl_xor for partner distance <64
//      (in-wave, register-resident), LDS exchange for s >= 64. Result in LDS.
//   2) SINGLE-WAVE bisection (tid < 64, zero barriers): each lane owns 8 j's
//      (j = lane + 64w) with warm-started brackets [A_w,B_w] on
//      L_j(x) = first i with fl(v[j]-v[i]) <= x (monotone in i after sort,
//      monotone in x). count(x) = sum_j (j - L_j). The 8 search chains are
//      independent -> their LDS loads pipeline. Block total via 6-step
//      __shfl_xor butterfly (every lane gets it; uniform decision).
//   median(squared diffs) = Dk*Dk (x -> fl(x^2) monotone on non-neg floats)
// ---------------------------------------------------------------------------
__global__ void __launch_bounds__(512)
median_bw_kernel(const float* __restrict__ particles, float* __restrict__ inv_bw)
{
    const int d   = blockIdx.x;     // 0..127
    const int tid = threadIdx.x;    // 0..511

    __shared__ float v[NP];

    float r = particles[tid * DD + d];

    // ---- hybrid bitonic sort ascending (n = 512) ----
    for (int k = 2; k <= NP; k <<= 1) {
        for (int s = k >> 1; s > 0; s >>= 1) {
            float other;
            if (s < 64) {
                other = __shfl_xor(r, s);       // in-wave, no barrier
            } else {
                __syncthreads();                // WAR: prior reads of v done
                v[tid] = r;
                __syncthreads();
                other = v[tid ^ s];
            }
            const bool lower = (tid & s) == 0;  // this thread is the low lane
            const bool up    = (tid & k) == 0;  // ascending sub-block
            r = (lower == up) ? fminf(r, other) : fmaxf(r, other);
        }
    }
    __syncthreads();          // WAR against last cross-stage reads
    v[tid] = r;
    __syncthreads();          // sorted array visible to wave 0

    if (tid < 64) {
        const int lane  = tid;
        const int want1 = (NP * (NP - 1) / 2 - 1) / 2 + 1;  // rank 65408

        float vj[8];
        int   A[8], B[8];
        #pragma unroll
        for (int w = 0; w < 8; ++w) {
            const int j = lane + 64 * w;
            vj[w] = v[j];
            A[w]  = 0;
            B[w]  = j;      // "count 0" sentinel; L_j in [A,B]
        }

        const float maxd = v[NP - 1] - v[0];
        unsigned lo = 0u;
        unsigned hi = __float_as_uint(maxd) + 1u;   // answer in [lo, hi]

        while (lo < hi) {
            const unsigned mid = (lo + hi) >> 1;
            const float x = __uint_as_float(mid);

            int a[8], b[8];
            #pragma unroll
            for (int w = 0; w < 8; ++w) { a[w] = A[w]; b[w] = B[w]; }

            // 8 independent binary-search chains, stepped in lockstep so the
            // LDS loads of one step issue together (pipelined latency)
            for (int step = 0; step < 10; ++step) {
                bool any = false;
                #pragma unroll
                for (int w = 0; w < 8; ++w) {
                    if (a[w] < b[w]) {
                        const int m = (a[w] + b[w]) >> 1;
                        const float pv = v[m];
                        if (vj[w] - pv <= x) b[w] = m; else a[w] = m + 1;
                        any = true;
                    }
                }
                if (!any) break;
            }

            int cnt = 0;
            #pragma unroll
            for (int w = 0; w < 8; ++w) cnt += (lane + 64 * w) - a[w];

            // butterfly: every lane ends with the block-wide total
            #pragma unroll
            for (int off = 1; off < 64; off <<= 1)
                cnt += __shfl_xor(cnt, off);

            if (cnt >= want1) {
                hi = mid;
                #pragma unroll
                for (int w = 0; w < 8; ++w) A[w] = a[w];  // x shrinks -> L grows
            } else {
                lo = mid + 1u;
                #pragma unroll
                for (int w = 0; w < 8; ++w) B[w] = a[w];  // x grows -> L shrinks
            }
        }

        if (lane == 0) {
            const float Dk     = __uint_as_float(lo); // k-th smallest |diff|
            const float median = Dk * Dk;             // k-th smallest sq diff
            const float h      = median / 6.240275844172107f;  // ln(513)
            const float bw     = fmaxf(h, 1e-9f);
            inv_bw[d] = 1.0f / bw;
        }
    }
}

// ---------------------------------------------------------------------------
// Kernel 2: write log_kernel and grad_log_kernel, float4-vectorized,
// nontemporal stores (write-once 268 MB stream, no reuse).
// Flat float4 index t over (i, j, d4):  d4 = t & 31, j = (t>>5)&511, i = t>>14
// ---------------------------------------------------------------------------
__global__ void __launch_bounds__(256)
stein_out_kernel(const float* __restrict__ particles,
                 const float* __restrict__ inv_bw,
                 float4* __restrict__ out_lk,
                 float4* __restrict__ out_g)
{
    const float4* __restrict__ p4  = (const float4*)particles;
    const float4* __restrict__ ib4 = (const float4*)inv_bw;
    const int total = NP * NP * (DD / 4);   // 8,388,608

    for (int t = blockIdx.x * blockDim.x + threadIdx.x; t < total;
         t += gridDim.x * blockDim.x) {
        const int d4 = t & (DD / 4 - 1);        // 0..31
        const int j  = (t >> 5) & (NP - 1);     // 0..511
        const int i  = t >> 14;                 // 0..511

        const float4 xj = p4[j * (DD / 4) + d4];
        const float4 xi = p4[i * (DD / 4) + d4];
        const float4 ib = ib4[d4];

        float4 lk, g;
        {
            const float dx = xj.x - xi.x;
            lk.x = -(dx * dx * ib.x);
            g.x  = -2.0f * dx * ib.x;
        }
        {
            const float dx = xj.y - xi.y;
            lk.y = -(dx * dx * ib.y);
            g.y  = -2.0f * dx * ib.y;
        }
        {
            const float dx = xj.z - xi.z;
            lk.z = -(dx * dx * ib.z);
            g.z  = -2.0f * dx * ib.z;
        }
        {
            const float dx = xj.w - xi.w;
            lk.w = -(dx * dx * ib.w);
            g.w  = -2.0f * dx * ib.w;
        }
        __builtin_nontemporal_store(*(const f4_ext*)&lk, (f4_ext*)&out_lk[t]);
        __builtin_nontemporal_store(*(const f4_ext*)&g,  (f4_ext*)&out_g[t]);
    }
}

extern "C" void kernel_launch(void* const* d_in, const int* in_sizes, int n_in,
                              void* d_out, int out_size, void* d_ws, size_t ws_size,
                              hipStream_t stream)
{
    const float* particles = (const float*)d_in[0];
    float* out    = (float*)d_out;
    float* inv_bw = (float*)d_ws;   // 128 floats of scratch

    median_bw_kernel<<<DD, 512, 0, stream>>>(particles, inv_bw);

    float4* out_lk = (float4*)out;
    float4* out_g  = (float4*)(out + (size_t)NP * NP * DD);
    stein_out_kernel<<<2048, 256, 0, stream>>>(particles, inv_bw, out_lk, out_g);
}

// Round 5
// 126.419 us; speedup vs baseline: 1.0442x; 1.0442x over previous
//
#include <hip/hip_runtime.h>
#include <hip/hip_bf16.h>

#define NP 512   // particles
#define DD 128   // dims

// ---------------------------------------------------------------------------
// Kernel 1: per-dimension exact median of upper-triangular pairwise squared
// differences. One block (512 threads) per dimension d.
//   1) hybrid bitonic sort of 512 values: __shfl_xor for partner distance <64
//      (in-wave, register-resident), LDS exchange for s >= 64. Result in LDS.
//   2) SINGLE-WAVE bisection (tid < 64, zero barriers): each lane owns 8 j's
//      (j = lane + 64w) with warm-started brackets [A_w,B_w] on
//      L_j(x) = first i with fl(v[j]-v[i]) <= x (monotone in i after sort,
//      monotone in x). count(x) = sum_j (j - L_j). The 8 search chains are
//      independent -> their LDS loads pipeline. Block total via 6-step
//      __shfl_xor butterfly (every lane gets it; uniform decision).
//   median(squared diffs) = Dk*Dk (x -> fl(x^2) monotone on non-neg floats)
// ---------------------------------------------------------------------------
__global__ void __launch_bounds__(512)
median_bw_kernel(const float* __restrict__ particles, float* __restrict__ inv_bw)
{
    const int d   = blockIdx.x;     // 0..127
    const int tid = threadIdx.x;    // 0..511

    __shared__ float v[NP];

    float r = particles[tid * DD + d];

    // ---- hybrid bitonic sort ascending (n = 512) ----
    for (int k = 2; k <= NP; k <<= 1) {
        for (int s = k >> 1; s > 0; s >>= 1) {
            float other;
            if (s < 64) {
                other = __shfl_xor(r, s);       // in-wave, no barrier
            } else {
                __syncthreads();                // WAR: prior reads of v done
                v[tid] = r;
                __syncthreads();
                other = v[tid ^ s];
            }
            const bool lower = (tid & s) == 0;  // this thread is the low lane
            const bool up    = (tid & k) == 0;  // ascending sub-block
            r = (lower == up) ? fminf(r, other) : fmaxf(r, other);
        }
    }
    __syncthreads();          // WAR against last cross-stage reads
    v[tid] = r;
    __syncthreads();          // sorted array visible to wave 0

    if (tid < 64) {
        const int lane  = tid;
        const int want1 = (NP * (NP - 1) / 2 - 1) / 2 + 1;  // rank 65408

        float vj[8];
        int   A[8], B[8];
        #pragma unroll
        for (int w = 0; w < 8; ++w) {
            const int j = lane + 64 * w;
            vj[w] = v[j];
            A[w]  = 0;
            B[w]  = j;      // "count 0" sentinel; L_j in [A,B]
        }

        const float maxd = v[NP - 1] - v[0];
        unsigned lo = 0u;
        unsigned hi = __float_as_uint(maxd) + 1u;   // answer in [lo, hi]

        while (lo < hi) {
            const unsigned mid = (lo + hi) >> 1;
            const float x = __uint_as_float(mid);

            int a[8], b[8];
            #pragma unroll
            for (int w = 0; w < 8; ++w) { a[w] = A[w]; b[w] = B[w]; }

            // 8 independent binary-search chains, stepped in lockstep so the
            // LDS loads of one step issue together (pipelined latency)
            for (int step = 0; step < 10; ++step) {
                bool any = false;
                #pragma unroll
                for (int w = 0; w < 8; ++w) {
                    if (a[w] < b[w]) {
                        const int m = (a[w] + b[w]) >> 1;
                        const float pv = v[m];
                        if (vj[w] - pv <= x) b[w] = m; else a[w] = m + 1;
                        any = true;
                    }
                }
                if (!any) break;
            }

            int cnt = 0;
            #pragma unroll
            for (int w = 0; w < 8; ++w) cnt += (lane + 64 * w) - a[w];

            // butterfly: every lane ends with the block-wide total
            #pragma unroll
            for (int off = 1; off < 64; off <<= 1)
                cnt += __shfl_xor(cnt, off);

            if (cnt >= want1) {
                hi = mid;
                #pragma unroll
                for (int w = 0; w < 8; ++w) A[w] = a[w];  // x shrinks -> L grows
            } else {
                lo = mid + 1u;
                #pragma unroll
                for (int w = 0; w < 8; ++w) B[w] = a[w];  // x grows -> L shrinks
            }
        }

        if (lane == 0) {
            const float Dk     = __uint_as_float(lo); // k-th smallest |diff|
            const float median = Dk * Dk;             // k-th smallest sq diff
            const float h      = median / 6.240275844172107f;  // ln(513)
            const float bw     = fmaxf(h, 1e-9f);
            inv_bw[d] = 1.0f / bw;
        }
    }
}

// ---------------------------------------------------------------------------
// Kernel 2: write log_kernel and grad_log_kernel, float4-vectorized,
// PLAIN stores (nontemporal stores regressed write BW ~2.4x in R4 — they
// bypass L2 write-combining, so 16B/lane stores are not merged into lines).
// Flat float4 index t over (i, j, d4):  d4 = t & 31, j = (t>>5)&511, i = t>>14
// ---------------------------------------------------------------------------
__global__ void __launch_bounds__(256)
stein_out_kernel(const float* __restrict__ particles,
                 const float* __restrict__ inv_bw,
                 float4* __restrict__ out_lk,
                 float4* __restrict__ out_g)
{
    const float4* __restrict__ p4  = (const float4*)particles;
    const float4* __restrict__ ib4 = (const float4*)inv_bw;
    const int total = NP * NP * (DD / 4);   // 8,388,608

    for (int t = blockIdx.x * blockDim.x + threadIdx.x; t < total;
         t += gridDim.x * blockDim.x) {
        const int d4 = t & (DD / 4 - 1);        // 0..31
        const int j  = (t >> 5) & (NP - 1);     // 0..511
        const int i  = t >> 14;                 // 0..511

        const float4 xj = p4[j * (DD / 4) + d4];
        const float4 xi = p4[i * (DD / 4) + d4];
        const float4 ib = ib4[d4];

        float4 lk, g;
        {
            const float dx = xj.x - xi.x;
            lk.x = -(dx * dx * ib.x);
            g.x  = -2.0f * dx * ib.x;
        }
        {
            const float dx = xj.y - xi.y;
            lk.y = -(dx * dx * ib.y);
            g.y  = -2.0f * dx * ib.y;
        }
        {
            const float dx = xj.z - xi.z;
            lk.z = -(dx * dx * ib.z);
            g.z  = -2.0f * dx * ib.z;
        }
        {
            const float dx = xj.w - xi.w;
            lk.w = -(dx * dx * ib.w);
            g.w  = -2.0f * dx * ib.w;
        }
        out_lk[t] = lk;
        out_g[t]  = g;
    }
}

extern "C" void kernel_launch(void* const* d_in, const int* in_sizes, int n_in,
                              void* d_out, int out_size, void* d_ws, size_t ws_size,
                              hipStream_t stream)
{
    const float* particles = (const float*)d_in[0];
    float* out    = (float*)d_out;
    float* inv_bw = (float*)d_ws;   // 128 floats of scratch

    median_bw_kernel<<<DD, 512, 0, stream>>>(particles, inv_bw);

    float4* out_lk = (float4*)out;
    float4* out_g  = (float4*)(out + (size_t)NP * NP * DD);
    stein_out_kernel<<<2048, 256, 0, stream>>>(particles, inv_bw, out_lk, out_g);
}

// Round 6
// 73.746 us; speedup vs baseline: 1.7901x; 1.7143x over previous
//
#include <hip/hip_runtime.h>
#include <hip/hip_bf16.h>

#define NP 512   // particles
#define DD 128   // dims

// ---------------------------------------------------------------------------
// Kernel 1: per-dimension exact median of upper-triangular pairwise squared
// differences. One block (512 threads) per dimension d.
//   1) hybrid bitonic sort of 512 values: __shfl_xor for partner distance <64
//      (in-wave, register-resident), LDS exchange for s >= 64. Result in LDS.
//   2) 4-ary bisection on float bit patterns of the k-th smallest pairwise
//      diff (rank want1 = (m-1)//2+1, m = N(N-1)/2): per round evaluate
//      count(x) at the 3 quartile pivots of [lo,hi], narrowing 2 bits/round
//      (~16 rounds vs 31 binary). Each thread owns one j and runs 3
//      BRANCH-FREE select-only search chains for
//      L_j(x) = first i with fl(v[j]-v[i]) <= x   (monotone in i and in x),
//      warm-started from bracket [A,B] maintained across rounds.
//      count(x) = sum_j (j - L_j(x)). 3 butterfly reduces + double-buffered
//      wave partials -> exactly 1 barrier per round.
//   median(squared diffs) = Dk*Dk (x -> fl(x^2) monotone on non-neg floats)
// ---------------------------------------------------------------------------
__global__ void __launch_bounds__(512)
median_bw_kernel(const float* __restrict__ particles, float* __restrict__ inv_bw)
{
    const int d   = blockIdx.x;     // 0..127
    const int tid = threadIdx.x;    // 0..511

    __shared__ float v[NP];
    __shared__ int   cnt_s[2][8][3];

    float r = particles[tid * DD + d];

    // ---- hybrid bitonic sort ascending (n = 512) ----
    for (int k = 2; k <= NP; k <<= 1) {
        for (int s = k >> 1; s > 0; s >>= 1) {
            float other;
            if (s < 64) {
                other = __shfl_xor(r, s);       // in-wave, no barrier
            } else {
                __syncthreads();                // WAR: prior reads of v done
                v[tid] = r;
                __syncthreads();
                other = v[tid ^ s];
            }
            const bool lower = (tid & s) == 0;  // this thread is the low lane
            const bool up    = (tid & k) == 0;  // ascending sub-block
            r = (lower == up) ? fminf(r, other) : fmaxf(r, other);
        }
    }
    __syncthreads();          // WAR against last cross-stage reads
    v[tid] = r;
    __syncthreads();          // sorted array visible to all

    const float vj = r;       // sorted value owned by this thread (j = tid)
    const int want1 = (NP * (NP - 1) / 2 - 1) / 2 + 1;   // rank 65408 (1-based)

    const float maxd = v[NP - 1] - v[0];
    unsigned lo = 0u;
    unsigned hi = __float_as_uint(maxd) + 1u;   // answer in [lo, hi]

    // Bracket invariant: A <= L_j(x) <= B for all candidate x in [lo, hi].
    int A = 0, B = tid;       // B = tid is the "count 0" sentinel
    int buf = 0;

    while (lo < hi) {
        const unsigned span = hi - lo;
        const unsigned q  = span >> 2;
        const unsigned m1 = lo + q;          // m1 <= m2 <= m3 < hi
        const unsigned m2 = lo + 2 * q;
        const unsigned m3 = lo + 3 * q;
        const float x1 = __uint_as_float(m1);
        const float x2 = __uint_as_float(m2);
        const float x3 = __uint_as_float(m3);

        // 3 branch-free search chains (straight-line: loads batch per step)
        int a1 = A, b1 = B, a2 = A, b2 = B, a3 = A, b3 = B;
        while (__any((a1 < b1) | (a2 < b2) | (a3 < b3))) {
            const int mm1 = (a1 + b1) >> 1;
            const int mm2 = (a2 + b2) >> 1;
            const int mm3 = (a3 + b3) >> 1;
            const float p1 = v[mm1];
            const float p2 = v[mm2];
            const float p3 = v[mm3];
            const bool g1 = a1 < b1, g2 = a2 < b2, g3 = a3 < b3;
            const bool t1 = (vj - p1 <= x1);
            const bool t2 = (vj - p2 <= x2);
            const bool t3 = (vj - p3 <= x3);
            b1 = (g1 &&  t1) ? mm1     : b1;
            a1 = (g1 && !t1) ? mm1 + 1 : a1;
            b2 = (g2 &&  t2) ? mm2     : b2;
            a2 = (g2 && !t2) ? mm2 + 1 : a2;
            b3 = (g3 &&  t3) ? mm3     : b3;
            a3 = (g3 && !t3) ? mm3 + 1 : a3;
        }
        // a1 >= a2 >= a3  (L decreasing in x)

        int c1 = tid - a1, c2 = tid - a2, c3 = tid - a3;
        #pragma unroll
        for (int off = 32; off > 0; off >>= 1) {
            c1 += __shfl_down(c1, off);
            c2 += __shfl_down(c2, off);
            c3 += __shfl_down(c3, off);
        }
        if ((tid & 63) == 0) {
            cnt_s[buf][tid >> 6][0] = c1;
            cnt_s[buf][tid >> 6][1] = c2;
            cnt_s[buf][tid >> 6][2] = c3;
        }
        __syncthreads();     // the ONLY barrier in the round

        int T1 = 0, T2 = 0, T3 = 0;
        #pragma unroll
        for (int w = 0; w < 8; ++w) {
            T1 += cnt_s[buf][w][0];
            T2 += cnt_s[buf][w][1];
            T3 += cnt_s[buf][w][2];
        }
        // uniform decision; T1 <= T2 <= T3 (count monotone in x)
        if (T1 >= want1)      { hi = m1;            A = a1;          }
        else if (T2 >= want1) { lo = m1 + 1; hi = m2; A = a2; B = a1; }
        else if (T3 >= want1) { lo = m2 + 1; hi = m3; A = a3; B = a2; }
        else                  { lo = m3 + 1;                  B = a3; }
        buf ^= 1;
    }

    if (tid == 0) {
        const float Dk     = __uint_as_float(lo); // k-th smallest |diff|
        const float median = Dk * Dk;             // k-th smallest sq diff
        const float h      = median / 6.240275844172107f;  // ln(513)
        const float bw     = fmaxf(h, 1e-9f);
        inv_bw[d] = 1.0f / bw;
    }
}

// ---------------------------------------------------------------------------
// Kernel 2: write log_kernel and grad_log_kernel, float4-vectorized,
// PLAIN stores (nontemporal stores regressed write BW ~2.4x in R4 — they
// bypass L2 write-combining, so 16B/lane stores are not merged into lines).
// Flat float4 index t over (i, j, d4):  d4 = t & 31, j = (t>>5)&511, i = t>>14
// ---------------------------------------------------------------------------
__global__ void __launch_bounds__(256)
stein_out_kernel(const float* __restrict__ particles,
                 const float* __restrict__ inv_bw,
                 float4* __restrict__ out_lk,
                 float4* __restrict__ out_g)
{
    const float4* __restrict__ p4  = (const float4*)particles;
    const float4* __restrict__ ib4 = (const float4*)inv_bw;
    const int total = NP * NP * (DD / 4);   // 8,388,608

    for (int t = blockIdx.x * blockDim.x + threadIdx.x; t < total;
         t += gridDim.x * blockDim.x) {
        const int d4 = t & (DD / 4 - 1);        // 0..31
        const int j  = (t >> 5) & (NP - 1);     // 0..511
        const int i  = t >> 14;                 // 0..511

        const float4 xj = p4[j * (DD / 4) + d4];
        const float4 xi = p4[i * (DD / 4) + d4];
        const float4 ib = ib4[d4];

        float4 lk, g;
        {
            const float dx = xj.x - xi.x;
            lk.x = -(dx * dx * ib.x);
            g.x  = -2.0f * dx * ib.x;
        }
        {
            const float dx = xj.y - xi.y;
            lk.y = -(dx * dx * ib.y);
            g.y  = -2.0f * dx * ib.y;
        }
        {
            const float dx = xj.z - xi.z;
            lk.z = -(dx * dx * ib.z);
            g.z  = -2.0f * dx * ib.z;
        }
        {
            const float dx = xj.w - xi.w;
            lk.w = -(dx * dx * ib.w);
            g.w  = -2.0f * dx * ib.w;
        }
        out_lk[t] = lk;
        out_g[t]  = g;
    }
}

extern "C" void kernel_launch(void* const* d_in, const int* in_sizes, int n_in,
                              void* d_out, int out_size, void* d_ws, size_t ws_size,
                              hipStream_t stream)
{
    const float* particles = (const float*)d_in[0];
    float* out    = (float*)d_out;
    float* inv_bw = (float*)d_ws;   // 128 floats of scratch

    median_bw_kernel<<<DD, 512, 0, stream>>>(particles, inv_bw);

    float4* out_lk = (float4*)out;
    float4* out_g  = (float4*)(out + (size_t)NP * NP * DD);
    stein_out_kernel<<<2048, 256, 0, stream>>>(particles, inv_bw, out_lk, out_g);
}

// Round 7
// 71.681 us; speedup vs baseline: 1.8417x; 1.0288x over previous
//
#include <hip/hip_runtime.h>
#include <hip/hip_bf16.h>

#define NP 512   // particles
#define DD 128   // dims

// Hybrid bitonic sort of 512 floats: value in register r (one per thread),
// __shfl_xor for partner distance < 64 (in-wave), LDS exchange for s >= 64.
// lds must be a 512-float scratch array; contents clobbered.
__device__ __forceinline__ float bitonic512(float r, int tid, float* lds)
{
    for (int k = 2; k <= NP; k <<= 1) {
        for (int s = k >> 1; s > 0; s >>= 1) {
            float other;
            if (s < 64) {
                other = __shfl_xor(r, s);       // in-wave, no barrier
            } else {
                __syncthreads();                // WAR vs prior reads of lds
                lds[tid] = r;
                __syncthreads();
                other = lds[tid ^ s];
            }
            const bool lower = (tid & s) == 0;
            const bool up    = (tid & k) == 0;
            r = (lower == up) ? fminf(r, other) : fmaxf(r, other);
        }
    }
    return r;
}

// ---------------------------------------------------------------------------
// Kernel 1: per-dimension exact median of upper-triangular pairwise squared
// differences. One block (512 threads) per dimension d.
//   1) bitonic sort values -> v[] (LDS), register copy vj per thread (j=tid)
//   2) bisection on float bits of the rank-want1 pairwise diff, with:
//      - forced pivots r0/r1 = min/max of offset-150 diffs (rank-65408 pair
//        sits at sorted-offset ~150; guess is VERIFIED by counts, so
//        correctness never depends on it)
//      - then alternating count-interpolation / bit-midpoint pivots
//      - per-j warm brackets A=L_j(hi), B=L_j(pred lo) (L monotone in i,x)
//      - count(x) = sum_j (j - L_j(x)); butterfly + 1 barrier per round
//   3) endgame: when T = C_hi - C_lo <= 512 candidates, gather them to LDS
//      (prefix-sum offsets), bitonic sort, answer = rank (want1-C_lo)
//   median(squared diffs) = Dk*Dk (x -> fl(x^2) monotone on non-neg floats)
// ---------------------------------------------------------------------------
__global__ void __launch_bounds__(512)
median_bw_kernel(const float* __restrict__ particles, float* __restrict__ inv_bw)
{
    const int d    = blockIdx.x;      // 0..127
    const int tid  = threadIdx.x;     // 0..511
    const int lane = tid & 63;
    const int wid  = tid >> 6;

    __shared__ float v[NP];
    __shared__ float cand[NP];
    __shared__ int   cnt_s[2][8];
    __shared__ float red_s[2][8];
    __shared__ int   scan_s[8];

    float r = particles[tid * DD + d];
    r = bitonic512(r, tid, v);
    __syncthreads();          // WAR vs last cross-stage reads inside sort
    v[tid] = r;
    __syncthreads();          // sorted array visible to all

    const float vj = r;       // sorted value owned by this thread (j = tid)
    const int want1 = (NP * (NP - 1) / 2 - 1) / 2 + 1;   // 65408 (1-based)

    // ---- offset-150 diff min/max -> statistical init pivots ----
    const float d150 = (tid >= 150) ? (vj - v[tid - 150]) : 0.0f;
    float dmn = (tid >= 150) ? d150 : INFINITY;
    float dmx = d150;
    #pragma unroll
    for (int off = 32; off > 0; off >>= 1) {
        dmn = fminf(dmn, __shfl_xor(dmn, off));
        dmx = fmaxf(dmx, __shfl_xor(dmx, off));
    }
    if (lane == 0) { red_s[0][wid] = dmn; red_s[1][wid] = dmx; }
    __syncthreads();
    float g_mn = INFINITY, g_mx = 0.0f;
    #pragma unroll
    for (int w = 0; w < 8; ++w) {
        g_mn = fminf(g_mn, red_s[0][w]);
        g_mx = fmaxf(g_mx, red_s[1][w]);
    }   // uniform across block

    const float maxd = v[NP - 1] - v[0];
    unsigned lo = 0u;
    unsigned hi = __float_as_uint(maxd) + 1u;   // answer bits in [lo, hi]
    int C_lo = 0;                   // C(pred(lo))  (< want1 invariant)
    int C_hi = NP * (NP - 1) / 2;   // C(hi)        (>= want1 invariant)
    int A = 0, B = tid;             // per-j window: L_j(hi)=A, L_j(pred lo)=B
    int buf = 0, round = 0;
    int T = C_hi - C_lo;

    while (lo < hi) {
        T = C_hi - C_lo;
        if (T <= NP) break;         // endgame: enumerate candidates

        unsigned mid;
        if (round == 0)      mid = __float_as_uint(g_mn);
        else if (round == 1) mid = __float_as_uint(g_mx);
        else if (round & 1) {       // count-interpolation (value space)
            const float flo  = __uint_as_float(lo);
            const float fhi  = __uint_as_float(hi);
            const float frac = (float)(want1 - C_lo) / (float)(C_hi - C_lo);
            mid = __float_as_uint(flo + (fhi - flo) * frac);
        } else {                    // safeguard: bit midpoint
            mid = lo + ((hi - lo) >> 1);
        }
        if (mid < lo)     mid = lo;
        if (mid > hi - 1) mid = hi - 1;

        const float x = __uint_as_float(mid);
        int a = A, b = B;
        while (a < b) {             // warm-started lower_bound (select-only)
            const int   m  = (a + b) >> 1;
            const float pv = v[m];
            const bool  t  = (vj - pv <= x);
            b = t ? m : b;
            a = t ? a : m + 1;
        }
        int cnt = tid - a;          // #{i<j : fl(vj-vi) <= x}

        #pragma unroll
        for (int off = 32; off > 0; off >>= 1) cnt += __shfl_down(cnt, off);
        if (lane == 0) cnt_s[buf][wid] = cnt;
        __syncthreads();            // the ONLY barrier in the round
        int tot = 0;
        #pragma unroll
        for (int w = 0; w < 8; ++w) tot += cnt_s[buf][w];

        if (tot >= want1) { hi = mid;      C_hi = tot; A = a; }
        else              { lo = mid + 1u; C_lo = tot; B = a; }
        buf ^= 1;
        ++round;
    }

    if (lo >= hi) {
        // bracket collapsed to a single bit pattern: that's the answer
        if (tid == 0) {
            const float Dk = __uint_as_float(lo);
            const float h  = (Dk * Dk) / 6.240275844172107f;  // ln(513)
            inv_bw[d] = 1.0f / fmaxf(h, 1e-9f);
        }
    } else {
        // ---- endgame: T (<=512) candidates, rank rr within them ----
        const int rr = want1 - C_lo;     // 1-based, 1 <= rr <= T
        const int n  = B - A;            // this thread's candidate count
        int inc = n;                     // wave inclusive scan
        #pragma unroll
        for (int off = 1; off < 64; off <<= 1) {
            const int t = __shfl_up(inc, off);
            if (lane >= off) inc += t;
        }
        if (lane == 63) scan_s[wid] = inc;
        __syncthreads();
        int woff = 0;
        #pragma unroll
        for (int w = 0; w < 8; ++w) woff += (w < wid) ? scan_s[w] : 0;
        int off0 = woff + inc - n;       // exclusive global offset
        for (int i = A; i < B; ++i) cand[off0++] = vj - v[i];
        __syncthreads();

        float c = (tid < T) ? cand[tid] : INFINITY;
        c = bitonic512(c, tid, v);       // v reusable as scratch now

        if (tid == rr - 1) {
            const float Dk = c;
            const float h  = (Dk * Dk) / 6.240275844172107f;  // ln(513)
            inv_bw[d] = 1.0f / fmaxf(h, 1e-9f);
        }
    }
}

// ---------------------------------------------------------------------------
// Kernel 2: write log_kernel and grad_log_kernel, float4-vectorized,
// PLAIN stores (nontemporal stores regressed write BW ~2.4x in R4 — they
// bypass L2 write-combining, so 16B/lane stores are not merged into lines).
// Flat float4 index t over (i, j, d4):  d4 = t & 31, j = (t>>5)&511, i = t>>14
// ---------------------------------------------------------------------------
__global__ void __launch_bounds__(256)
stein_out_kernel(const float* __restrict__ particles,
                 const float* __restrict__ inv_bw,
                 float4* __restrict__ out_lk,
                 float4* __restrict__ out_g)
{
    const float4* __restrict__ p4  = (const float4*)particles;
    const float4* __restrict__ ib4 = (const float4*)inv_bw;
    const int total = NP * NP * (DD / 4);   // 8,388,608

    for (int t = blockIdx.x * blockDim.x + threadIdx.x; t < total;
         t += gridDim.x * blockDim.x) {
        const int d4 = t & (DD / 4 - 1);        // 0..31
        const int j  = (t >> 5) & (NP - 1);     // 0..511
        const int i  = t >> 14;                 // 0..511

        const float4 xj = p4[j * (DD / 4) + d4];
        const float4 xi = p4[i * (DD / 4) + d4];
        const float4 ib = ib4[d4];

        float4 lk, g;
        {
            const float dx = xj.x - xi.x;
            lk.x = -(dx * dx * ib.x);
            g.x  = -2.0f * dx * ib.x;
        }
        {
            const float dx = xj.y - xi.y;
            lk.y = -(dx * dx * ib.y);
            g.y  = -2.0f * dx * ib.y;
        }
        {
            const float dx = xj.z - xi.z;
            lk.z = -(dx * dx * ib.z);
            g.z  = -2.0f * dx * ib.z;
        }
        {
            const float dx = xj.w - xi.w;
            lk.w = -(dx * dx * ib.w);
            g.w  = -2.0f * dx * ib.w;
        }
        out_lk[t] = lk;
        out_g[t]  = g;
    }
}

extern "C" void kernel_launch(void* const* d_in, const int* in_sizes, int n_in,
                              void* d_out, int out_size, void* d_ws, size_t ws_size,
                              hipStream_t stream)
{
    const float* particles = (const float*)d_in[0];
    float* out    = (float*)d_out;
    float* inv_bw = (float*)d_ws;   // 128 floats of scratch

    median_bw_kernel<<<DD, 512, 0, stream>>>(particles, inv_bw);

    float4* out_lk = (float4*)out;
    float4* out_g  = (float4*)(out + (size_t)NP * NP * DD);
    stein_out_kernel<<<2048, 256, 0, stream>>>(particles, inv_bw, out_lk, out_g);
}